// Round 8
// baseline (128.106 us; speedup 1.0000x reference)
//
#include <hip/hip_runtime.h>
#include <hip/hip_bf16.h>
#include <math.h>

#define HDIM 100
#define NFACT 262144
#define FPB   128             // facts per block
#define NBLK  2048            // NFACT / FPB
#define NTHREADS 512          // 8 waves; wave w owns j-tile jt=w (jt=7 is zero-pad)

// K packed to 256: k in [0,128) -> (f - oc) (valid k<100), k in [128,256) -> (f - m)
// (valid k-128<100). Dead k ranges have B==0 and z==0.
#define KP   256
#define NKC  8
#define NJT  8
#define NBFRAG (NJT * NKC * 64)   // 4096 uint4

using short8 = __attribute__((ext_vector_type(8))) short;
using f32x4  = __attribute__((ext_vector_type(4))) float;

// ---------------- ws float-offset layout ----------------
#define WS_B    0                 // 16384 floats (4096 uint4 B-fragments, bf16 bits)
#define WS_ACC  16384             // 101 floats: corr[100] + S  (zeroed by k_prep_b)

__device__ __forceinline__ unsigned short f2bf(float x) {
    unsigned u = __builtin_bit_cast(unsigned, x);
    u += 0x7FFFu + ((u >> 16) & 1u);          // RNE round to bf16
    return (unsigned short)(u >> 16);
}

__device__ __forceinline__ float tanh_fast(float x) {
    float e = __expf(2.0f * x);
    return 1.0f - 2.0f / (1.0f + e);
}

// ---- Precompute W1 as MFMA B-fragments (bf16), frag order [jt][kc][lane][8] ----
// B[k][j]: j = jt*16 + (lane&15); k = kc*32 + (lane>>4)*8 + e.
__global__ __launch_bounds__(256) void k_prep_b(const float* __restrict__ W1,
                                                float* __restrict__ ws) {
    if (blockIdx.x == 0 && threadIdx.x < 128)
        ws[WS_ACC + threadIdx.x] = 0.f;       // zero accumulators every call
    int t = blockIdx.x * 256 + threadIdx.x;
    if (t >= NBFRAG) return;
    int lane = t & 63;
    int kc = (t >> 6) & 7;
    int jt = t >> 9;
    int g = lane >> 4, r = lane & 15;
    int j = jt * 16 + r;
    unsigned short v[8];
    #pragma unroll
    for (int e = 0; e < 8; e++) {
        int kglob = kc * 32 + g * 8 + e;
        int half = kglob >> 7;
        int koff = kglob & 127;
        float x = 0.f;
        if (j < HDIM && koff < HDIM) x = W1[j * 200 + half * HDIM + koff];
        v[e] = f2bf(x);
    }
    uint4 d;
    d.x = (unsigned)v[0] | ((unsigned)v[1] << 16);
    d.y = (unsigned)v[2] | ((unsigned)v[3] << 16);
    d.z = (unsigned)v[4] | ((unsigned)v[5] << 16);
    d.w = (unsigned)v[6] | ((unsigned)v[7] << 16);
    ((uint4*)(ws + WS_B))[t] = d;
}

// Fused: signed-z bf16 tile (XOR-swizzled, built once at staging) -> per-wave
// j-slice MFMA (B in 32 VGPR) -> softmax partials -> pooling from the SAME tile
// with exact oc*S correction. fe read exactly once, coalesced.
__global__ __launch_bounds__(NTHREADS, 4) void k_logits(
        const float* __restrict__ fe,
        const float* __restrict__ oc,
        const float* __restrict__ mvec,
        const float* __restrict__ b1,
        const float* __restrict__ W2,
        float* __restrict__ ws) {
    __shared__ uint4 zt4[FPB * 32];            // 64 KiB: [row][512B], byte^=(row&7)<<4
    __shared__ float gvp[NJT][FPB];
    __shared__ float wls[FPB];
    __shared__ float sred[2];
    __shared__ float poolbuf[4][128];

    char* zt = (char*)zt4;
    int t = threadIdx.x;
    int w = t >> 6, lane = t & 63, g = lane >> 4, r = lane & 15;
    long n0 = (long)blockIdx.x * FPB;

    // ---- this wave's B slice (jt = w): 8 uint4, loaded once (L2/L3-hot) ----
    uint4 bfrag[NKC];
    {
        const uint4* Bg = (const uint4*)(ws + WS_B);
        #pragma unroll
        for (int kc = 0; kc < NKC; kc++) bfrag[kc] = Bg[(w * NKC + kc) * 64 + lane];
    }
    int j = w * 16 + r;
    float w2j = (j < HDIM) ? W2[j] : 0.f;
    float b1j = (j < HDIM) ? b1[j] : 0.f;

    // ---- stage: signed diffs, bf16, swizzled. 4 threads per row. ----
    {
        int row = t >> 2;
        int sw = (row & 7) << 4;
        char* zrow = zt + row * 512;
        const float4* fr = (const float4*)(fe + n0 * HDIM) + row * 25;
        #pragma unroll
        for (int i = 0; i < 7; i++) {
            int c4 = (t & 3) + 4 * i;
            if (c4 < 25) {
                float4 f = fr[c4];
                float4 o = *(const float4*)(oc + c4 * 4);
                float4 mm = *(const float4*)(mvec + c4 * 4);
                uint2 z0, z1;
                z0.x = (unsigned)f2bf(f.x - o.x) | ((unsigned)f2bf(f.y - o.y) << 16);
                z0.y = (unsigned)f2bf(f.z - o.z) | ((unsigned)f2bf(f.w - o.w) << 16);
                z1.x = (unsigned)f2bf(f.x - mm.x) | ((unsigned)f2bf(f.y - mm.y) << 16);
                z1.y = (unsigned)f2bf(f.z - mm.z) | ((unsigned)f2bf(f.w - mm.w) << 16);
                int b = c4 * 8;
                *(uint2*)(zrow + (b ^ sw)) = z0;          // k = c4*4..+3
                *(uint2*)(zrow + 256 + (b ^ sw)) = z1;    // k = 128 + c4*4..+3
            }
        }
        // zero pads: k in [100,128) -> bytes 200..255; k in [228,256) -> 456..511
        for (int i = t; i < FPB * 14; i += NTHREADS) {
            int prow = i / 14, q = i % 14;
            int byte = (q < 7) ? (200 + q * 8) : (456 + (q - 7) * 8);
            int psw = (prow & 7) << 4;
            int hi = byte & 256, lo = byte & 255;
            *(uint2*)(zt + prow * 512 + hi + (lo ^ psw)) = make_uint2(0u, 0u);
        }
    }
    __syncthreads();

    // ---- GEMM: waves 0..6 each do 8 fact-tiles x 8 kc; abs via bf16 sign-mask ----
    if (w < 7) {
        #pragma unroll
        for (int tile = 0; tile < FPB / 16; tile++) {
            int row = tile * 16 + r;
            int sw = (row & 7) << 4;
            const char* zr = zt + row * 512;
            f32x4 acc = {0, 0, 0, 0};
            #pragma unroll
            for (int kc = 0; kc < NKC; kc++) {
                uint4 zv = *(const uint4*)(zr + ((kc * 64 + g * 16) ^ sw));
                zv.x &= 0x7FFF7FFFu; zv.y &= 0x7FFF7FFFu;
                zv.z &= 0x7FFF7FFFu; zv.w &= 0x7FFF7FFFu;
                acc = __builtin_amdgcn_mfma_f32_16x16x32_bf16(
                    __builtin_bit_cast(short8, zv),
                    __builtin_bit_cast(short8, bfrag[kc]), acc, 0, 0, 0);
            }
            #pragma unroll
            for (int q = 0; q < 4; q++) {
                float v = tanh_fast(acc[q] + b1j) * w2j;
                v += __shfl_xor(v, 1); v += __shfl_xor(v, 2);
                v += __shfl_xor(v, 4); v += __shfl_xor(v, 8);
                if (r == 0) gvp[w][tile * 16 + g * 4 + q] = v;
            }
        }
    } else {
        gvp[7][lane] = 0.f;
        gvp[7][64 + lane] = 0.f;
    }
    __syncthreads();

    // ---- logits -> exp (b2 dropped: softmax-invariant; |logit| <= sum|W2| ~ 8) ----
    float e = 0.f;
    if (t < FPB) {
        float l = gvp[0][t];
        #pragma unroll
        for (int jj = 1; jj < NJT; jj++) l += gvp[jj][t];
        e = __expf(l);
        wls[t] = e;
    }
    float s = e;
    #pragma unroll
    for (int off = 32; off; off >>= 1) s += __shfl_down(s, off);
    if (lane == 0 && t < FPB) sred[t >> 6] = s;
    __syncthreads();
    if (t == 0) atomicAdd(&ws[WS_ACC + HDIM], sred[0] + sred[1]);

    // ---- pooling from the SAME tile: corr[k] = sum_n wls[n] * (f-oc)[n][k] ----
    {
        int sl = t >> 7, k = t & 127;
        float corr = 0.f;
        #pragma unroll 8
        for (int n = sl * 32; n < sl * 32 + 32; n++) {
            int sw = (n & 7) << 4;
            unsigned short us = *(const unsigned short*)(zt + n * 512 + ((2 * k) ^ sw));
            float f = __builtin_bit_cast(float, ((unsigned)us) << 16);
            corr = fmaf(wls[n], f, corr);
        }
        poolbuf[sl][k] = corr;
    }
    __syncthreads();
    if (t < HDIM) {
        float c = poolbuf[0][t] + poolbuf[1][t] + poolbuf[2][t] + poolbuf[3][t];
        atomicAdd(&ws[WS_ACC + t], c);
    }
}

// Tiny epilogue: c/S = oc + corr/S; gated update. One block.
__global__ __launch_bounds__(128) void k_final(
        const float* __restrict__ mvec,
        const float* __restrict__ oc,
        const float* __restrict__ W3,
        const float* __restrict__ b3,
        const float* __restrict__ ws,
        float* __restrict__ out) {
    __shared__ float vv[300];
    int t = threadIdx.x;
    float S = ws[WS_ACC + HDIM];
    if (t < HDIM) {
        vv[t] = mvec[t];
        vv[HDIM + t] = oc[t] + ws[WS_ACC + t] / S;
        vv[2 * HDIM + t] = oc[t];
    }
    __syncthreads();
    if (t < HDIM) {
        float a = b3[t];
        const float* wr = W3 + t * 3 * HDIM;
        #pragma unroll 4
        for (int k = 0; k < 3 * HDIM; k++) a = fmaf(wr[k], vv[k], a);
        out[t] = fmaxf(a, 0.f);
    }
}

extern "C" void kernel_launch(void* const* d_in, const int* in_sizes, int n_in,
                              void* d_out, int out_size, void* d_ws, size_t ws_size,
                              hipStream_t stream) {
    const float* mvec = (const float*)d_in[0];
    const float* oh   = (const float*)d_in[1];
    const float* fe   = (const float*)d_in[2];
    const float* W1   = (const float*)d_in[3];
    const float* b1   = (const float*)d_in[4];
    const float* W2   = (const float*)d_in[5];
    const float* W3   = (const float*)d_in[7];
    const float* b3   = (const float*)d_in[8];
    float* ws  = (float*)d_ws;
    float* out = (float*)d_out;

    k_prep_b<<<16, 256, 0, stream>>>(W1, ws);
    k_logits<<<NBLK, NTHREADS, 0, stream>>>(fe, oh, mvec, b1, W2, ws);
    k_final<<<1, 128, 0, stream>>>(mvec, oh, W3, b3, ws, out);
}

// Round 9
// 109.316 us; speedup vs baseline: 1.1719x; 1.1719x over previous
//
#include <hip/hip_runtime.h>
#include <hip/hip_bf16.h>
#include <math.h>

#define HDIM 100
#define NFACT 262144
#define FPB   128             // facts per block
#define NBLK  2048            // NFACT / FPB
#define NTHREADS 512          // 8 waves; wave w owns facts [w*16, w*16+16), ALL j

// K packed to 256: k in [0,128) -> (f - oc) (valid k<100), k in [128,256) -> (f - m).
// Dead k ranges have B==0 and z==0.
#define NJT 7                 // j-tiles of 16 (112 >= 100)
#define NKC 8
#define NBFRAG (NJT * NKC * 64)   // 3584 uint4

using short8 = __attribute__((ext_vector_type(8))) short;
using f32x4  = __attribute__((ext_vector_type(4))) float;

// ---------------- ws float-offset layout ----------------
#define WS_B    0                 // 14336 floats (3584 uint4 W1-fragments, bf16 bits)
#define WS_ACC  14336             // 101 floats: corr[100] + S (zeroed by k_prep_b)

__device__ __forceinline__ unsigned short f2bf(float x) {
    unsigned u = __builtin_bit_cast(unsigned, x);
    u += 0x7FFFu + ((u >> 16) & 1u);          // RNE round to bf16
    return (unsigned short)(u >> 16);
}

__device__ __forceinline__ float tanh_fast(float x) {
    float e = __expf(2.0f * x);
    return 1.0f - 2.0f / (1.0f + e);
}

// ---- Precompute W1 fragments (bf16), order [jt][kc][lane][8] ----
// Used as the MFMA *A* operand: A[row=j][k]; per lane: j = jt*16 + (lane&15),
// k = kc*32 + (lane>>4)*8 + e.
__global__ __launch_bounds__(256) void k_prep_b(const float* __restrict__ W1,
                                                float* __restrict__ ws) {
    if (blockIdx.x == 0 && threadIdx.x < 104)
        ws[WS_ACC + threadIdx.x] = 0.f;       // zero accumulators every call
    int t = blockIdx.x * 256 + threadIdx.x;
    if (t >= NBFRAG) return;
    int lane = t & 63;
    int kc = (t >> 6) & 7;
    int jt = t >> 9;
    int g = lane >> 4, r = lane & 15;
    int j = jt * 16 + r;
    unsigned short v[8];
    #pragma unroll
    for (int e = 0; e < 8; e++) {
        int kglob = kc * 32 + g * 8 + e;
        int half = kglob >> 7;
        int koff = kglob & 127;
        float x = 0.f;
        if (j < HDIM && koff < HDIM) x = W1[j * 200 + half * HDIM + koff];
        v[e] = f2bf(x);
    }
    uint4 d;
    d.x = (unsigned)v[0] | ((unsigned)v[1] << 16);
    d.y = (unsigned)v[2] | ((unsigned)v[3] << 16);
    d.z = (unsigned)v[4] | ((unsigned)v[5] << 16);
    d.w = (unsigned)v[6] | ((unsigned)v[7] << 16);
    ((uint4*)(ws + WS_B))[t] = d;
}

__device__ __forceinline__ float4 ld4c(const float* p, bool ok) {
    float4 z = make_float4(0.f, 0.f, 0.f, 0.f);
    return ok ? *(const float4*)p : z;
}

__device__ __forceinline__ short8 pack_diff(float4 a0, float4 a1,
                                            float4 b0, float4 b1) {
    union { unsigned short us[8]; short8 v; } u;
    u.us[0] = f2bf(a0.x - b0.x); u.us[1] = f2bf(a0.y - b0.y);
    u.us[2] = f2bf(a0.z - b0.z); u.us[3] = f2bf(a0.w - b0.w);
    u.us[4] = f2bf(a1.x - b1.x); u.us[5] = f2bf(a1.y - b1.y);
    u.us[6] = f2bf(a1.z - b1.z); u.us[7] = f2bf(a1.w - b1.w);
    return u.v;
}

// DPP row-rotate add (VALU pipe): x + rotate_within_16(x, N)
template<int CTRL>
__device__ __forceinline__ float dpp_radd(float x) {
    int y = __builtin_amdgcn_update_dpp(0, __builtin_bit_cast(int, x),
                                        CTRL, 0xF, 0xF, true);
    return x + __builtin_bit_cast(float, y);
}
__device__ __forceinline__ float row_reduce16(float x) {
    x = dpp_radd<0x121>(x);   // row_ror:1
    x = dpp_radd<0x122>(x);   // row_ror:2
    x = dpp_radd<0x124>(x);   // row_ror:4
    x = dpp_radd<0x128>(x);   // row_ror:8
    return x;                 // all 16 lanes of the row hold the row-sum
}

#define P2S 36                // pool2 slice stride (floats): 144 B, 16B-aligned, banks spread

// One wave = 16 facts, all j, everything in-wave. 2 barriers total.
__global__ __launch_bounds__(NTHREADS, 4) void k_logits(
        const float* __restrict__ fe,
        const float* __restrict__ oc,
        const float* __restrict__ mvec,
        const float* __restrict__ b1,
        const float* __restrict__ W2,
        float* __restrict__ ws) {
    __shared__ uint4 Bs[NBFRAG];              // 57344 B (W1 fragments)
    __shared__ float pool2[32 * P2S];         // (w*4+c)*P2S + g*8+e  — 4608 B
    __shared__ float sS;

    int t = threadIdx.x;
    int w = t >> 6, lane = t & 63, g = lane >> 4, r = lane & 15;
    long n0 = (long)blockIdx.x * FPB;

    if (t == 0) sS = 0.f;

    // ---- issue W1-table loads (coalesced, L2/L3-hot) ----
    const uint4* Bg = (const uint4*)(ws + WS_B);
    uint4 breg[7];
    #pragma unroll
    for (int i = 0; i < 7; i++) breg[i] = Bg[t + i * 512];

    // ---- issue this lane's fact-row loads (cols c*32+g*8 .. +8) ----
    const float* fp = fe + (n0 + w * 16 + r) * HDIM;
    float4 fa[4], fb[4], oa[4], ob[4], ma[4], mb[4];
    #pragma unroll
    for (int c = 0; c < 4; c++) {
        int base = c * 32 + g * 8;
        bool v0 = base < HDIM, v1 = base + 4 < HDIM;
        fa[c] = ld4c(fp + base, v0);   fb[c] = ld4c(fp + base + 4, v1);
        oa[c] = ld4c(oc + base, v0);   ob[c] = ld4c(oc + base + 4, v1);
        ma[c] = ld4c(mvec + base, v0); mb[c] = ld4c(mvec + base + 4, v1);
    }

    // ---- W1 table -> LDS ----
    #pragma unroll
    for (int i = 0; i < 7; i++) Bs[t + i * 512] = breg[i];
    __syncthreads();

    // ---- signed z in registers (bf16): zoc = f-oc (k<128), zm = f-m (k>=128) ----
    short8 zoc[4], zm[4];
    #pragma unroll
    for (int c = 0; c < 4; c++) {
        zoc[c] = pack_diff(fa[c], fb[c], oa[c], ob[c]);
        zm[c]  = pack_diff(fa[c], fb[c], ma[c], mb[c]);
    }

    // ---- GEMM: C[j][fact] = mfma(W1frag, zfrag); abs applied at use ----
    float gacc = 0.f;
    #pragma unroll
    for (int jt = 0; jt < NJT; jt++) {
        f32x4 acc = {0, 0, 0, 0};
        #pragma unroll
        for (int kc = 0; kc < NKC; kc++) {
            uint4 zu = __builtin_bit_cast(uint4, (kc < 4) ? zoc[kc] : zm[kc - 4]);
            zu.x &= 0x7FFF7FFFu; zu.y &= 0x7FFF7FFFu;
            zu.z &= 0x7FFF7FFFu; zu.w &= 0x7FFF7FFFu;
            short8 av = __builtin_bit_cast(short8, Bs[(jt * 8 + kc) * 64 + lane]);
            acc = __builtin_amdgcn_mfma_f32_16x16x32_bf16(
                av, __builtin_bit_cast(short8, zu), acc, 0, 0, 0);
        }
        #pragma unroll
        for (int q = 0; q < 4; q++) {
            int j = jt * 16 + g * 4 + q;          // C row = j, C col = r = my fact
            float w2j = (j < HDIM) ? W2[j] : 0.f;
            float b1j = (j < HDIM) ? b1[j] : 0.f;
            gacc = fmaf(tanh_fast(acc[q] + b1j), w2j, gacc);
        }
    }
    // sum partial logits over the 4 g-groups -> logit of fact (n0 + w*16 + r)
    gacc += __shfl_xor(gacc, 16);
    gacc += __shfl_xor(gacc, 32);
    float w_r = __expf(gacc);     // b2 dropped (softmax-invariant); |logit| <= sum|W2| ~ 8

    // ---- S partial: sum w_r over r (DPP), one atomic per wave ----
    float s16 = row_reduce16(w_r);
    if (lane == 0) atomicAdd(&sS, s16);

    // ---- pooling from z regs: p[k] = sum_r w_r * (f-oc)[r][k], k = c*32+g*8+e ----
    float p[4][8];
    #pragma unroll
    for (int c = 0; c < 4; c++) {
        union { short8 v; unsigned short us[8]; } uz; uz.v = zoc[c];
        #pragma unroll
        for (int e = 0; e < 8; e++) {
            float zf = __builtin_bit_cast(float, ((unsigned)uz.us[e]) << 16);
            p[c][e] = w_r * zf;
        }
    }
    #pragma unroll
    for (int c = 0; c < 4; c++)
        #pragma unroll
        for (int e = 0; e < 8; e++) p[c][e] = row_reduce16(p[c][e]);

    if (r == 0) {   // 4 g-lanes write their 32 k-slots, conflict-free, 16B-aligned
        #pragma unroll
        for (int c = 0; c < 4; c++) {
            float* dst = pool2 + (w * 4 + c) * P2S + g * 8;
            *(float4*)(dst)     = make_float4(p[c][0], p[c][1], p[c][2], p[c][3]);
            *(float4*)(dst + 4) = make_float4(p[c][4], p[c][5], p[c][6], p[c][7]);
        }
    }
    __syncthreads();

    // ---- block flush: one global atomic per k (+1 for S) ----
    if (t < 128) {
        int c = t >> 5, off = t & 31;             // k = c*32 + off
        float a = 0.f;
        #pragma unroll
        for (int w8 = 0; w8 < 8; w8++) a += pool2[(w8 * 4 + c) * P2S + off];
        if (t < HDIM) atomicAdd(&ws[WS_ACC + t], a);
    }
    if (t == 0) atomicAdd(&ws[WS_ACC + HDIM], sS);
}

// Tiny epilogue: c = oc + corr/S; gated update. One block.
__global__ __launch_bounds__(128) void k_final(
        const float* __restrict__ mvec,
        const float* __restrict__ oc,
        const float* __restrict__ W3,
        const float* __restrict__ b3,
        const float* __restrict__ ws,
        float* __restrict__ out) {
    __shared__ float vv[300];
    int t = threadIdx.x;
    float S = ws[WS_ACC + HDIM];
    if (t < HDIM) {
        vv[t] = mvec[t];
        vv[HDIM + t] = oc[t] + ws[WS_ACC + t] / S;
        vv[2 * HDIM + t] = oc[t];
    }
    __syncthreads();
    if (t < HDIM) {
        float a = b3[t];
        const float* wr = W3 + t * 3 * HDIM;
        #pragma unroll 4
        for (int k = 0; k < 3 * HDIM; k++) a = fmaf(wr[k], vv[k], a);
        out[t] = fmaxf(a, 0.f);
    }
}

extern "C" void kernel_launch(void* const* d_in, const int* in_sizes, int n_in,
                              void* d_out, int out_size, void* d_ws, size_t ws_size,
                              hipStream_t stream) {
    const float* mvec = (const float*)d_in[0];
    const float* oh   = (const float*)d_in[1];
    const float* fe   = (const float*)d_in[2];
    const float* W1   = (const float*)d_in[3];
    const float* b1   = (const float*)d_in[4];
    const float* W2   = (const float*)d_in[5];
    const float* W3   = (const float*)d_in[7];
    const float* b3   = (const float*)d_in[8];
    float* ws  = (float*)d_ws;
    float* out = (float*)d_out;

    k_prep_b<<<14, 256, 0, stream>>>(W1, ws);
    k_logits<<<NBLK, NTHREADS, 0, stream>>>(fe, oh, mvec, b1, W2, ws);
    k_final<<<1, 128, 0, stream>>>(mvec, oh, W3, b3, ws, out);
}